// Round 1
// baseline (396.063 us; speedup 1.0000x reference)
//
#include <hip/hip_runtime.h>

// ---------------- workspace layout (floats) ----------------
#define WS_WT    0          // 640*64 = 40960 transposed w1x1 [c][o]
#define WS_WSUM  40960      // 64 row sums of w1x1
#define WS_FB    41024      // 8*100*64 = 51200   fb [b][hw][o]
#define WS_FM    92224      // 50*100*64 = 320000 fm [n][ij][o]
#define WS_CORR  412224     // 400*10000 = 4000000 corr / corr2 (in-place)
#define WS_ATTN  4412224    // 400*100 = 40000  attn_memory [q][ij]
#define WS_AM    4452224    // 8*50*640 = 256000 att_mem [b][n][c]
#define WS_ENC   4708224    // 8*640 = 5120
#define WS_MV    4713344    // 8*640 = 5120
// total 4718464 floats = ~18.9 MB

// ---------------- prep: transpose w1x1 + row sums ----------------
__global__ void k_prep(const float* __restrict__ w1x1, float* __restrict__ wT,
                       float* __restrict__ wsum) {
  if (blockIdx.x < 160) {
    int idx = blockIdx.x * 256 + threadIdx.x;   // < 40960
    int o = idx / 640, c = idx % 640;
    wT[c * 64 + o] = w1x1[idx];
  } else {
    int o = threadIdx.x;
    if (o < 64) {
      float s = 0.f;
      for (int c = 0; c < 640; ++c) s += w1x1[o * 640 + c];
      wsum[o] = s;
    }
  }
}

// ---------------- embed: mean-shift + 1x1 conv + BN + ReLU + L2 norm ----------
// grid 580 blocks (10 positions each), block = 64 (one wave, lane = out channel)
__global__ void k_embed(const float* __restrict__ fbg, const float* __restrict__ fmg,
                        const float* __restrict__ wT, const float* __restrict__ wsum,
                        const float* __restrict__ bns, const float* __restrict__ bnb,
                        float* __restrict__ fb, float* __restrict__ fm) {
  int lane = threadIdx.x;
  int pos0 = blockIdx.x * 10;
  const float* src; float* dst; int hw0;
  if (pos0 < 800) { int img = pos0 / 100; hw0 = pos0 % 100; src = fbg + img * 64000; dst = fb + pos0 * 64; }
  else { int p = pos0 - 800; int img = p / 100; hw0 = p % 100; src = fmg + img * 64000; dst = fm + p * 64; }

  __shared__ float xs[10][640];
  float lsum[10];
#pragma unroll
  for (int p = 0; p < 10; ++p) lsum[p] = 0.f;
  for (int i = 0; i < 10; ++i) {
    int c = lane + i * 64;
    const float* sp = src + c * 100 + hw0;
#pragma unroll
    for (int p = 0; p < 10; p += 2) {
      float2 v = *(const float2*)(sp + p);
      xs[p][c] = v.x; xs[p + 1][c] = v.y;
      lsum[p] += v.x; lsum[p + 1] += v.y;
    }
  }
  float mean[10];
#pragma unroll
  for (int p = 0; p < 10; ++p) {
    float s = lsum[p];
    for (int off = 32; off; off >>= 1) s += __shfl_down(s, off);
    mean[p] = __shfl(s, 0) * (1.f / 640.f);
  }
  __syncthreads();
  float acc[10];
#pragma unroll
  for (int p = 0; p < 10; ++p) acc[p] = 0.f;
  for (int c = 0; c < 640; ++c) {
    float w = wT[c * 64 + lane];
#pragma unroll
    for (int p = 0; p < 10; ++p) acc[p] += xs[p][c] * w;
  }
  float wsl = wsum[lane], sc = bns[lane], bi = bnb[lane];
#pragma unroll
  for (int p = 0; p < 10; ++p) {
    float y = (acc[p] - mean[p] * wsl) * sc + bi;
    y = fmaxf(y, 0.f);
    float sq = y * y;
    for (int off = 32; off; off >>= 1) sq += __shfl_down(sq, off);
    float nrm = sqrtf(__shfl(sq, 0));
    dst[p * 64 + lane] = y / fmaxf(nrm, 1e-8f);
  }
}

// ---------------- corr: [q][ij][hw] = dot64(fm[n][ij], fb[b][hw]) -------------
__global__ void k_corr(const float* __restrict__ fb, const float* __restrict__ fm,
                       float* __restrict__ corr) {
  int q = blockIdx.x, b = q / 50, n = q % 50;
  __shared__ float fbs[100 * 72];  // padded stride 72 to break bank aliasing
  __shared__ float fms[100 * 72];
  for (int idx = threadIdx.x; idx < 6400; idx += 256) {
    int pos = idx >> 6, o = idx & 63;
    fbs[pos * 72 + o] = fb[b * 6400 + idx];
    fms[pos * 72 + o] = fm[n * 6400 + idx];
  }
  __syncthreads();
  float* out = corr + q * 10000;
  for (int p = threadIdx.x; p < 10000; p += 256) {
    int ij = p / 100, hw = p % 100;
    const float4* A  = (const float4*)(fms + ij * 72);
    const float4* Bv = (const float4*)(fbs + hw * 72);
    float acc = 0.f;
#pragma unroll
    for (int t = 0; t < 16; ++t) {
      float4 a = A[t], c = Bv[t];
      acc += a.x * c.x + a.y * c.y + a.z * c.z + a.w * c.w;
    }
    out[p] = acc;
  }
}

// ---------------- fused separable 4D conv: relu(conv1(x)) -> conv2, in place --
// grid 400 (one q per block), block 1024, thread t owns w-row r=t (<1000)
__global__ __launch_bounds__(1024, 1) void k_conv(float* __restrict__ corr,
    const float* __restrict__ w1h_g, const float* __restrict__ w1u_g,
    const float* __restrict__ w2h_g, const float* __restrict__ w2u_g) {
  __shared__ float xs[10000];
  __shared__ float c1[10000];
  __shared__ float w1h[144], w1u[144], w2h[144], w2u[144];
  int q = blockIdx.x, tid = threadIdx.x;
  float* g = corr + q * 10000;
  for (int i = tid; i < 10000; i += 1024) xs[i] = g[i];
  if (tid < 144) { w1h[tid] = w1h_g[tid]; w1u[tid] = w1u_g[tid];
                   w2h[tid] = w2h_g[tid]; w2u[tid] = w2u_g[tid]; }
  __syncthreads();
  int r = tid;
  bool act = r < 1000;
  int u = r / 100, v = (r / 10) % 10, h = r % 10;
  float xh[3][12];
  float acc[10];
  if (act) {
#pragma unroll
    for (int ky = 0; ky < 3; ++ky) {
#pragma unroll
      for (int j = 0; j < 12; ++j) xh[ky][j] = 0.f;
      int hh = h + ky - 1;
      if (hh >= 0 && hh < 10) {
        int base = (u * 100 + v * 10 + hh) * 10;
#pragma unroll
        for (int w = 0; w < 10; ++w) xh[ky][w + 1] = xs[base + w];
      }
    }
#pragma unroll
    for (int w = 0; w < 10; ++w) acc[w] = 0.f;
  }
  for (int k = 0; k < 16; ++k) {
    if (act) {
      float o[10];
#pragma unroll
      for (int w = 0; w < 10; ++w) {
        float s = 0.f;
#pragma unroll
        for (int ky = 0; ky < 3; ++ky)
#pragma unroll
          for (int kx = 0; kx < 3; ++kx)
            s += xh[ky][w + kx] * w1h[k * 9 + ky * 3 + kx];
        o[w] = s;
      }
#pragma unroll
      for (int dy = 0; dy < 3; ++dy) {
        int uu = u + dy - 1;
        if (uu < 0 || uu >= 10) continue;
#pragma unroll
        for (int dx = 0; dx < 3; ++dx) {
          int vv = v + dx - 1;
          if (vv < 0 || vv >= 10) continue;
          float wgt = w1u[k * 9 + dy * 3 + dx];
          int base = (uu * 100 + vv * 10 + h) * 10;
#pragma unroll
          for (int w = 0; w < 10; ++w) o[w] += xs[base + w] * wgt;
        }
      }
      int base = r * 10;
#pragma unroll
      for (int w = 0; w < 10; ++w) c1[base + w] = fmaxf(o[w], 0.f);
    }
    __syncthreads();
    if (act) {
#pragma unroll
      for (int ky = 0; ky < 3; ++ky) {
        int hh = h + ky - 1;
        if (hh < 0 || hh >= 10) continue;
        int base = (u * 100 + v * 10 + hh) * 10;
        float rowh[12];
        rowh[0] = 0.f; rowh[11] = 0.f;
#pragma unroll
        for (int w = 0; w < 10; ++w) rowh[w + 1] = c1[base + w];
#pragma unroll
        for (int kx = 0; kx < 3; ++kx) {
          float wgt = w2h[k * 9 + ky * 3 + kx];
#pragma unroll
          for (int w = 0; w < 10; ++w) acc[w] += rowh[w + kx] * wgt;
        }
      }
#pragma unroll
      for (int dy = 0; dy < 3; ++dy) {
        int uu = u + dy - 1;
        if (uu < 0 || uu >= 10) continue;
#pragma unroll
        for (int dx = 0; dx < 3; ++dx) {
          int vv = v + dx - 1;
          if (vv < 0 || vv >= 10) continue;
          float wgt = w2u[k * 9 + dy * 3 + dx];
          int base = (uu * 100 + vv * 10 + h) * 10;
#pragma unroll
          for (int w = 0; w < 10; ++w) acc[w] += c1[base + w] * wgt;
        }
      }
    }
    __syncthreads();
  }
  if (act) {
    int base = r * 10;
#pragma unroll
    for (int w = 0; w < 10; ++w) g[base + w] = acc[w];
  }
}

// ---------------- attention over memory positions (cb path is dead code) -----
// per (b,n): gaussian-normalize over ij (unbiased), /5, softmax over ij, sum hw
__global__ void k_attn(const float* __restrict__ corr, float* __restrict__ attn) {
  int q = blockIdx.x;
  __shared__ float m[10000];
  const float* g = corr + q * 10000;
  for (int i = threadIdx.x; i < 10000; i += 128) m[i] = g[i];
  __syncthreads();
  int t = threadIdx.x;
  if (t < 100) {
    float s = 0.f;
    for (int ij = 0; ij < 100; ++ij) s += m[ij * 100 + t];
    float mean = s * 0.01f;
    float vs = 0.f, mx = -1e30f;
    for (int ij = 0; ij < 100; ++ij) {
      float d = m[ij * 100 + t] - mean;
      vs += d * d;
      mx = fmaxf(mx, d);
    }
    float inv = 1.f / (5.f * sqrtf(vs * (1.f / 99.f) + 1e-5f));
    float es = 0.f;
    for (int ij = 0; ij < 100; ++ij) {
      float e = expf((m[ij * 100 + t] - mean - mx) * inv);
      m[ij * 100 + t] = e; es += e;
    }
    float rr = 1.f / es;
    for (int ij = 0; ij < 100; ++ij) m[ij * 100 + t] *= rr;
  }
  __syncthreads();
  if (t < 100) {
    float s = 0.f;
    const float* row = m + t * 100;
    for (int hw = 0; hw < 100; ++hw) s += row[hw];
    attn[q * 100 + t] = s;
  }
}

// ---------------- att_mem[b,n,c] = sum_ij attn*feat_m / 100 ------------------
__global__ void k_attmem(const float* __restrict__ attn, const float* __restrict__ fmg,
                         float* __restrict__ am) {
  int q = blockIdx.x, n = q % 50;
  __shared__ float a[100];
  if (threadIdx.x < 100) a[threadIdx.x] = attn[q * 100 + threadIdx.x];
  __syncthreads();
  for (int c = threadIdx.x; c < 640; c += 256) {
    const float* fp = fmg + (n * 640 + c) * 100;
    float s = 0.f;
#pragma unroll 4
    for (int ij = 0; ij < 100; ++ij) s += a[ij] * fp[ij];
    am[q * 640 + c] = s * 0.01f;
  }
}

// ---------------- encoder_output = spatial mean of feat_b --------------------
__global__ void k_enc(const float* __restrict__ fbg, float* __restrict__ enc) {
  int b = blockIdx.x;
  for (int c = threadIdx.x; c < 640; c += 256) {
    const float* fp = fbg + (b * 640 + c) * 100;
    float s = 0.f;
    for (int hw = 0; hw < 100; ++hw) s += fp[hw];
    enc[b * 640 + c] = s * 0.01f;
  }
}

// ---------------- cosine sim + softmax over memory + mem_vec -----------------
__global__ void k_final1(const float* __restrict__ enc, const float* __restrict__ am,
                         float* __restrict__ mv) {
  int b = blockIdx.x, tid = threadIdx.x;
  __shared__ float e[640];
  __shared__ float wsm[50];
  __shared__ float wred[4];
  for (int c = tid; c < 640; c += 256) e[c] = enc[b * 640 + c];
  __syncthreads();
  float ps = 0.f;
  for (int c = tid; c < 640; c += 256) { float x = e[c]; ps += x * x; }
  for (int off = 32; off; off >>= 1) ps += __shfl_down(ps, off);
  if ((tid & 63) == 0) wred[tid >> 6] = ps;
  __syncthreads();
  float en = fmaxf(sqrtf(wred[0] + wred[1] + wred[2] + wred[3]), 1e-8f);
  if (tid < 50) {
    const float* ap = am + (b * 50 + tid) * 640;
    float dot = 0.f, nn = 0.f;
    for (int c = 0; c < 640; ++c) { float x = ap[c]; dot += x * e[c]; nn += x * x; }
    wsm[tid] = dot / (en * fmaxf(sqrtf(nn), 1e-8f));
  }
  __syncthreads();
  if (tid == 0) {
    float mx = -1e30f;
    for (int n = 0; n < 50; ++n) mx = fmaxf(mx, wsm[n]);
    float es = 0.f;
    for (int n = 0; n < 50; ++n) { float ex = expf(wsm[n] - mx); wsm[n] = ex; es += ex; }
    float rr = 1.f / es;
    for (int n = 0; n < 50; ++n) wsm[n] *= rr;
  }
  __syncthreads();
  for (int c = tid; c < 640; c += 256) {
    float s = 0.f;
    for (int n = 0; n < 50; ++n) s += wsm[n] * am[(b * 50 + n) * 640 + c];
    mv[b * 640 + c] = s;
  }
}

// ---------------- logits = concat(enc, mem_vec) @ W_fc + b_fc ----------------
__global__ void k_final2(const float* __restrict__ enc, const float* __restrict__ mv,
                         const float* __restrict__ Wfc, const float* __restrict__ bfc,
                         float* __restrict__ out) {
  int b = blockIdx.x >> 2, jc = blockIdx.x & 3;
  __shared__ float cat[1280];
  for (int c = threadIdx.x; c < 640; c += 256) {
    cat[c] = enc[b * 640 + c];
    cat[640 + c] = mv[b * 640 + c];
  }
  __syncthreads();
  if (threadIdx.x < 250) {
    int j = jc * 250 + threadIdx.x;
    float s = bfc[j];
    for (int c = 0; c < 1280; ++c) s += cat[c] * Wfc[c * 1000 + j];
    out[b * 1000 + j] = s;
  }
}

extern "C" void kernel_launch(void* const* d_in, const int* in_sizes, int n_in,
                              void* d_out, int out_size, void* d_ws, size_t ws_size,
                              hipStream_t stream) {
  const float* feat_b = (const float*)d_in[0];
  const float* feat_m = (const float*)d_in[1];
  const float* w1x1   = (const float*)d_in[2];
  const float* bns    = (const float*)d_in[3];
  const float* bnb    = (const float*)d_in[4];
  const float* w1h    = (const float*)d_in[5];
  const float* w1u    = (const float*)d_in[6];
  const float* w2h    = (const float*)d_in[7];
  const float* w2u    = (const float*)d_in[8];
  const float* Wfc    = (const float*)d_in[9];
  const float* bfc    = (const float*)d_in[10];
  float* ws = (float*)d_ws;
  float* wT   = ws + WS_WT;   float* wsum = ws + WS_WSUM;
  float* fb   = ws + WS_FB;   float* fm   = ws + WS_FM;
  float* corr = ws + WS_CORR; float* attn = ws + WS_ATTN;
  float* am   = ws + WS_AM;   float* enc  = ws + WS_ENC;
  float* mv   = ws + WS_MV;

  k_prep  <<<161, 256, 0, stream>>>(w1x1, wT, wsum);
  k_embed <<<580,  64, 0, stream>>>(feat_b, feat_m, wT, wsum, bns, bnb, fb, fm);
  k_corr  <<<400, 256, 0, stream>>>(fb, fm, corr);
  k_conv  <<<400, 1024, 0, stream>>>(corr, w1h, w1u, w2h, w2u);
  k_attn  <<<400, 128, 0, stream>>>(corr, attn);
  k_attmem<<<400, 256, 0, stream>>>(attn, feat_m, am);
  k_enc   <<<8,   256, 0, stream>>>(feat_b, enc);
  k_final1<<<8,   256, 0, stream>>>(enc, am, mv);
  k_final2<<<32,  256, 0, stream>>>(enc, mv, Wfc, bfc, (float*)d_out);
}